// Round 1
// baseline (229.388 us; speedup 1.0000x reference)
//
#include <hip/hip_runtime.h>
#include <math.h>

#define IN_DIM   16
#define OUT_DIM  64
#define EXP_DIM  273            // 1 + 16 + 256
#define N_NODES  50000
#define N_EDGES  400000
#define SCALE    0.1f
#define SQRT2C   1.41421356237309515f   // sqrt(2*c), c = 1.0

// ---------------------------------------------------------------------------
// Kernel A: y = poly2(features) @ proj ; out = 0.25 * y  (residual term)
// One block = 256 threads = 4 waves; block handles 64 nodes (16 per wave).
// lane = output column o. proj staged in LDS (69888 B), features in LDS (4 KB).
// ---------------------------------------------------------------------------
__global__ __launch_bounds__(256) void node_proj_kernel(
    const float* __restrict__ features, const float* __restrict__ proj,
    float* __restrict__ y, float* __restrict__ out)
{
    __shared__ float sP[EXP_DIM * OUT_DIM];   // 273*64*4 = 69888 B
    __shared__ float sF[64 * IN_DIM];         // 4 KB

    const int tid = threadIdx.x;

    // cooperative load of proj into LDS
    for (int idx = tid; idx < EXP_DIM * OUT_DIM; idx += 256)
        sP[idx] = proj[idx];

    const int node0 = blockIdx.x * 64;
    for (int idx = tid; idx < 64 * IN_DIM; idx += 256) {
        int n = node0 + (idx >> 4);
        sF[idx] = (n < N_NODES) ? features[n * IN_DIM + (idx & 15)] : 0.0f;
    }
    __syncthreads();

    const int wave = tid >> 6;
    const int lane = tid & 63;

    for (int k = 0; k < 16; ++k) {
        const int ln = wave * 16 + k;       // local node index 0..63
        const int n  = node0 + ln;
        if (n >= N_NODES) break;

        float z[IN_DIM];
        #pragma unroll
        for (int i = 0; i < IN_DIM; ++i)
            z[i] = SCALE * sF[ln * IN_DIM + i];

        // const term: c * P[0]
        float acc = sP[0 * OUT_DIM + lane];

        // linear terms: sqrt(2c) * z_i * P[1+i]
        #pragma unroll
        for (int i = 0; i < IN_DIM; ++i)
            acc += (SQRT2C * z[i]) * sP[(1 + i) * OUT_DIM + lane];

        // quadratic terms: z_i z_j * P[17 + i*16 + j]
        #pragma unroll
        for (int i = 0; i < IN_DIM; ++i) {
            const float zi = z[i];
            #pragma unroll
            for (int j = 0; j < IN_DIM; ++j)
                acc += (zi * z[j]) * sP[(17 + i * 16 + j) * OUT_DIM + lane];
        }

        y[n * OUT_DIM + lane]   = acc;
        out[n * OUT_DIM + lane] = 0.25f * acc;   // residual, pre-scaled by 1/sqrt(16)
    }
}

// ---------------------------------------------------------------------------
// Kernel B: out[dst] += 0.25 * y[src]  over all edges (scatter-add).
// One wave handles EPW edges; 64 lanes = 64 output columns (coalesced).
// ---------------------------------------------------------------------------
#define EPW 16   // edges per wave

__global__ __launch_bounds__(256) void edge_scatter_kernel(
    const int* __restrict__ src, const int* __restrict__ dst,
    const float* __restrict__ y, float* out)
{
    const int lane = threadIdx.x & 63;
    const int wid  = blockIdx.x * (blockDim.x >> 6) + (threadIdx.x >> 6);
    const int e0   = wid * EPW;

    #pragma unroll 1
    for (int k = 0; k < EPW; ++k) {
        const int e = e0 + k;
        if (e >= N_EDGES) return;
        const int s = src[e];
        const int d = dst[e];
        const float v = y[s * OUT_DIM + lane];
        atomicAdd(&out[d * OUT_DIM + lane], 0.25f * v);
    }
}

// ---------------------------------------------------------------------------
extern "C" void kernel_launch(void* const* d_in, const int* in_sizes, int n_in,
                              void* d_out, int out_size, void* d_ws, size_t ws_size,
                              hipStream_t stream)
{
    const float* features = (const float*)d_in[0];
    const int*   src      = (const int*)  d_in[1];
    const int*   dst      = (const int*)  d_in[2];
    const float* proj     = (const float*)d_in[3];

    float* out = (float*)d_out;
    float* y   = (float*)d_ws;   // 50000*64*4 = 12.8 MB scratch

    const int nodeBlocks = (N_NODES + 63) / 64;                  // 782
    node_proj_kernel<<<nodeBlocks, 256, 0, stream>>>(features, proj, y, out);

    const int wavesNeeded = (N_EDGES + EPW - 1) / EPW;           // 25000
    const int edgeBlocks  = (wavesNeeded + 3) / 4;               // 6250
    edge_scatter_kernel<<<edgeBlocks, 256, 0, stream>>>(src, dst, y, out);
}

// Round 2
// 122.843 us; speedup vs baseline: 1.8673x; 1.8673x over previous
//
#include <hip/hip_runtime.h>

#define IN_DIM   16
#define OUT_DIM  64
#define N_NODES  50000
#define N_EDGES  400000
#define SCALE    0.1f
#define SQRT2C   1.41421356237309515f   // sqrt(2*c), c = 1.0
#define KPAD     288                    // 9 * 32 (K-steps of mfma 16x16x32)
#define LDB      296                    // LDS row stride (fp16 elems), 592 B, 16B-aligned

typedef _Float16 f16x8 __attribute__((ext_vector_type(8)));
typedef float    f32x4 __attribute__((ext_vector_type(4)));

// ---------------------------------------------------------------------------
// Kernel A: y = poly2(features) @ proj via fp16 MFMA; out = 0.25*y (residual).
// K-permutation: t in [0,256): quad term (i=t>>4, j=t&15), orig row 17+t
//                t == 256   : const term, orig row 0
//                t in (256,273): linear term, orig row t-256
//                t in [273,288): zero pad
// Block = 256 thr = 4 waves; wave handles 16 nodes; block = 64 nodes.
// A-fragment built in registers from z; B staged in LDS as fp16 [col][k].
// ---------------------------------------------------------------------------
__global__ __launch_bounds__(256) void node_proj_mfma(
    const float* __restrict__ features, const float* __restrict__ proj,
    float* __restrict__ y, float* __restrict__ out)
{
    __shared__ _Float16 sB[OUT_DIM][LDB];   // 64*296*2 = 37888 B

    const int tid = threadIdx.x;

    // stage proj (reordered K, transposed, fp16). idx = t*64 + col → coalesced reads.
    for (int idx = tid; idx < OUT_DIM * KPAD; idx += 256) {
        const int t   = idx >> 6;
        const int col = idx & 63;
        float pv;
        if      (t < 256)  pv = proj[(17 + t) * OUT_DIM + col];
        else if (t == 256) pv = proj[0 * OUT_DIM + col];
        else if (t < 273)  pv = proj[(t - 256) * OUT_DIM + col];
        else               pv = 0.0f;
        sB[col][t] = (_Float16)pv;
    }
    __syncthreads();

    const int wave = tid >> 6;
    const int lane = tid & 63;
    const int kg   = lane >> 4;          // k-group 0..3
    const int bcol = lane & 15;

    // each lane holds z[0..15] of its node (node = node0 + wave*16 + (lane&15))
    const int node0  = blockIdx.x * 64;
    const int myNode = node0 + wave * 16 + (lane & 15);
    float z[IN_DIM];
    {
        const int n = (myNode < N_NODES) ? myNode : (N_NODES - 1);
        const float4* f4 = (const float4*)(features + n * IN_DIM);
        #pragma unroll
        for (int q = 0; q < 4; ++q) {
            float4 v = f4[q];
            z[q*4+0] = SCALE * v.x; z[q*4+1] = SCALE * v.y;
            z[q*4+2] = SCALE * v.z; z[q*4+3] = SCALE * v.w;
        }
    }

    f32x4 acc[4] = {};   // 4 N-tiles of 16 cols

    #pragma unroll
    for (int kk = 0; kk < 9; ++kk) {
        // ---- A fragment in registers: a[j] = h[node][kk*32 + kg*8 + j]
        f16x8 a;
        if (kk < 8) {
            const float zi = z[kk * 2 + (kg >> 1)];
            const int jb = (kg & 1) * 8;
            #pragma unroll
            for (int j = 0; j < 8; ++j)
                a[j] = (_Float16)(zi * z[jb + j]);
        } else {
            if (kg == 0) {
                a[0] = (_Float16)1.0f;
                #pragma unroll
                for (int j = 1; j < 8; ++j) a[j] = (_Float16)(SQRT2C * z[j - 1]);
            } else if (kg == 1) {
                #pragma unroll
                for (int j = 0; j < 8; ++j) a[j] = (_Float16)(SQRT2C * z[7 + j]);
            } else if (kg == 2) {
                a[0] = (_Float16)(SQRT2C * z[15]);
                #pragma unroll
                for (int j = 1; j < 8; ++j) a[j] = (_Float16)0.0f;
            } else {
                #pragma unroll
                for (int j = 0; j < 8; ++j) a[j] = (_Float16)0.0f;
            }
        }

        // ---- B fragments from LDS (b128), one per N-tile; MFMA
        #pragma unroll
        for (int nt = 0; nt < 4; ++nt) {
            const f16x8 b = *(const f16x8*)&sB[nt * 16 + bcol][kk * 32 + kg * 8];
            acc[nt] = __builtin_amdgcn_mfma_f32_16x16x32_f16(a, b, acc[nt], 0, 0, 0);
        }
    }

    // ---- epilogue: C/D layout col = lane&15 (+nt*16), row = (lane>>4)*4 + r
    #pragma unroll
    for (int nt = 0; nt < 4; ++nt) {
        #pragma unroll
        for (int r = 0; r < 4; ++r) {
            const int node = node0 + wave * 16 + (lane >> 4) * 4 + r;
            if (node < N_NODES) {
                const int c = nt * 16 + (lane & 15);
                const float v = acc[nt][r];
                y[node * OUT_DIM + c]   = v;
                out[node * OUT_DIM + c] = 0.25f * v;
            }
        }
    }
}

// ---------------------------------------------------------------------------
// Kernel B: out[dst] += 0.25*y[src]. One wave = 16 edges, lanes = 64 columns.
// All 16 index pairs loaded up front; 16 independent gathers in flight before
// the atomics (hides HBM/L2 latency).
// ---------------------------------------------------------------------------
#define EPW 16

__global__ __launch_bounds__(256) void edge_scatter_kernel(
    const int* __restrict__ src, const int* __restrict__ dst,
    const float* __restrict__ y, float* out)
{
    const int lane = threadIdx.x & 63;
    const int wid  = blockIdx.x * 4 + (threadIdx.x >> 6);
    const int e0   = wid * EPW;
    if (e0 >= N_EDGES) return;

    const int sI = src[e0 + (lane & 15)];
    const int dI = dst[e0 + (lane & 15)];

    float v[EPW];
    #pragma unroll
    for (int k = 0; k < EPW; ++k) {
        const int s = __shfl(sI, k, 64);
        v[k] = y[s * OUT_DIM + lane];
    }
    #pragma unroll
    for (int k = 0; k < EPW; ++k) {
        const int d = __shfl(dI, k, 64);
        atomicAdd(&out[d * OUT_DIM + lane], 0.25f * v[k]);
    }
}

// ---------------------------------------------------------------------------
extern "C" void kernel_launch(void* const* d_in, const int* in_sizes, int n_in,
                              void* d_out, int out_size, void* d_ws, size_t ws_size,
                              hipStream_t stream)
{
    const float* features = (const float*)d_in[0];
    const int*   src      = (const int*)  d_in[1];
    const int*   dst      = (const int*)  d_in[2];
    const float* proj     = (const float*)d_in[3];

    float* out = (float*)d_out;
    float* y   = (float*)d_ws;   // 50000*64*4 = 12.8 MB

    const int nodeBlocks = (N_NODES + 63) / 64;            // 782
    node_proj_mfma<<<nodeBlocks, 256, 0, stream>>>(features, proj, y, out);

    const int wavesNeeded = (N_EDGES + EPW - 1) / EPW;     // 25000
    const int edgeBlocks  = (wavesNeeded + 3) / 4;         // 6250
    edge_scatter_kernel<<<edgeBlocks, 256, 0, stream>>>(src, dst, y, out);
}

// Round 3
// 94.704 us; speedup vs baseline: 2.4222x; 1.2971x over previous
//
#include <hip/hip_runtime.h>

#define IN_DIM   16
#define OUT_DIM  64
#define N_NODES  50000
#define N_EDGES  400000
#define SCALE    0.1f
#define SQRT2C   1.41421356237309515f   // sqrt(2*c), c = 1.0
#define KPAD     288                    // 9 * 32 (K-steps of mfma 16x16x32)
#define LDB      296                    // LDS row stride (fp16 elems), 592 B, 16B-aligned
#define DEG_PAD  48                     // max in-degree slots (Poisson(8): P(>=48) ~ 1e-25)

typedef _Float16 f16x8 __attribute__((ext_vector_type(8)));
typedef float    f32x4 __attribute__((ext_vector_type(4)));

// ---------------------------------------------------------------------------
// Kernel A: y16 = fp16( poly2(features) @ proj ) via fp16 MFMA.
// K-permutation: t in [0,256): quad (i=t>>4, j=t&15) -> orig row 17+t
//                t == 256   : const -> orig row 0
//                t in (256,273): linear -> orig row t-256 ; [273,288): pad
// Block = 256 thr = 4 waves; wave handles 32 nodes (2 m-tiles); block = 128.
// ---------------------------------------------------------------------------
__global__ __launch_bounds__(256) void node_proj_mfma(
    const float* __restrict__ features, const float* __restrict__ proj,
    _Float16* __restrict__ y16)
{
    __shared__ _Float16 sB[OUT_DIM][LDB];   // 64*296*2 = 37888 B

    const int tid = threadIdx.x;

    // stage proj (reordered K, transposed, fp16); coalesced global reads
    for (int idx = tid; idx < OUT_DIM * KPAD; idx += 256) {
        const int t   = idx >> 6;
        const int col = idx & 63;
        float pv;
        if      (t < 256)  pv = proj[(17 + t) * OUT_DIM + col];
        else if (t == 256) pv = proj[0 * OUT_DIM + col];
        else if (t < 273)  pv = proj[(t - 256) * OUT_DIM + col];
        else               pv = 0.0f;
        sB[col][t] = (_Float16)pv;
    }
    __syncthreads();

    const int wave = tid >> 6;
    const int lane = tid & 63;
    const int kg   = lane >> 4;          // k-group 0..3
    const int bcol = lane & 15;

    const int m0 = blockIdx.x * 128 + wave * 32;   // first node of m-tile 0

    // z for this lane's node in each of the two m-tiles
    float z0[IN_DIM], z1[IN_DIM];
    {
        int n0 = m0 + (lane & 15);        if (n0 >= N_NODES) n0 = N_NODES - 1;
        int n1 = m0 + 16 + (lane & 15);   if (n1 >= N_NODES) n1 = N_NODES - 1;
        const float4* f0 = (const float4*)(features + n0 * IN_DIM);
        const float4* f1 = (const float4*)(features + n1 * IN_DIM);
        #pragma unroll
        for (int q = 0; q < 4; ++q) {
            float4 v0 = f0[q], v1 = f1[q];
            z0[q*4+0] = SCALE * v0.x; z0[q*4+1] = SCALE * v0.y;
            z0[q*4+2] = SCALE * v0.z; z0[q*4+3] = SCALE * v0.w;
            z1[q*4+0] = SCALE * v1.x; z1[q*4+1] = SCALE * v1.y;
            z1[q*4+2] = SCALE * v1.z; z1[q*4+3] = SCALE * v1.w;
        }
    }

    f32x4 acc0[4] = {};
    f32x4 acc1[4] = {};

    #pragma unroll
    for (int kk = 0; kk < 9; ++kk) {
        f16x8 a0, a1;
        if (kk < 8) {
            const int zi_idx = kk * 2 + (kg >> 1);
            const int jb     = (kg & 1) * 8;
            const float zi0 = z0[zi_idx], zi1 = z1[zi_idx];
            #pragma unroll
            for (int j = 0; j < 8; ++j) {
                a0[j] = (_Float16)(zi0 * z0[jb + j]);
                a1[j] = (_Float16)(zi1 * z1[jb + j]);
            }
        } else {
            if (kg == 0) {
                a0[0] = (_Float16)1.0f; a1[0] = (_Float16)1.0f;
                #pragma unroll
                for (int j = 1; j < 8; ++j) {
                    a0[j] = (_Float16)(SQRT2C * z0[j - 1]);
                    a1[j] = (_Float16)(SQRT2C * z1[j - 1]);
                }
            } else if (kg == 1) {
                #pragma unroll
                for (int j = 0; j < 8; ++j) {
                    a0[j] = (_Float16)(SQRT2C * z0[7 + j]);
                    a1[j] = (_Float16)(SQRT2C * z1[7 + j]);
                }
            } else if (kg == 2) {
                a0[0] = (_Float16)(SQRT2C * z0[15]);
                a1[0] = (_Float16)(SQRT2C * z1[15]);
                #pragma unroll
                for (int j = 1; j < 8; ++j) { a0[j] = (_Float16)0.0f; a1[j] = (_Float16)0.0f; }
            } else {
                #pragma unroll
                for (int j = 0; j < 8; ++j) { a0[j] = (_Float16)0.0f; a1[j] = (_Float16)0.0f; }
            }
        }

        #pragma unroll
        for (int nt = 0; nt < 4; ++nt) {
            const f16x8 b = *(const f16x8*)&sB[nt * 16 + bcol][kk * 32 + kg * 8];
            acc0[nt] = __builtin_amdgcn_mfma_f32_16x16x32_f16(a0, b, acc0[nt], 0, 0, 0);
            acc1[nt] = __builtin_amdgcn_mfma_f32_16x16x32_f16(a1, b, acc1[nt], 0, 0, 0);
        }
    }

    // epilogue: C/D layout row = kg*4 + r (node), col = nt*16 + bcol
    #pragma unroll
    for (int nt = 0; nt < 4; ++nt) {
        #pragma unroll
        for (int r = 0; r < 4; ++r) {
            const int c  = nt * 16 + bcol;
            const int nA = m0 + kg * 4 + r;
            const int nB = m0 + 16 + kg * 4 + r;
            if (nA < N_NODES) y16[nA * OUT_DIM + c] = (_Float16)acc0[nt][r];
            if (nB < N_NODES) y16[nB * OUT_DIM + c] = (_Float16)acc1[nt][r];
        }
    }
}

// ---------------------------------------------------------------------------
// Kernel B1: histogram + scatter src into padded per-dst slots (u16 ids).
// ---------------------------------------------------------------------------
__global__ __launch_bounds__(256) void hist_scatter(
    const int* __restrict__ src, const int* __restrict__ dst,
    int* __restrict__ cnt, unsigned short* __restrict__ eidx)
{
    const int e = blockIdx.x * 256 + threadIdx.x;
    if (e >= N_EDGES) return;
    const int d = dst[e];
    const int p = atomicAdd(&cnt[d], 1);
    if (p < DEG_PAD) eidx[d * DEG_PAD + p] = (unsigned short)src[e];
}

// ---------------------------------------------------------------------------
// Kernel B2: pull-aggregate. One wave per node; lanes = 64 output columns.
// out[n] = 0.25 * ( y[n] + sum_{e: dst=n} y[src_e] )
// ---------------------------------------------------------------------------
__global__ __launch_bounds__(256) void pull_kernel(
    const int* __restrict__ cnt, const unsigned short* __restrict__ eidx,
    const _Float16* __restrict__ y16, float* __restrict__ out)
{
    const int wave = threadIdx.x >> 6;
    const int lane = threadIdx.x & 63;
    const int n    = blockIdx.x * 4 + wave;
    if (n >= N_NODES) return;

    int deg = cnt[n];
    if (deg > DEG_PAD) deg = DEG_PAD;

    int myIdx = 0;
    if (lane < DEG_PAD) myIdx = eidx[n * DEG_PAD + lane];

    float sum = (float)y16[n * OUT_DIM + lane];   // residual term
    for (int k = 0; k < deg; ++k) {
        const int s = __shfl(myIdx, k, 64);
        sum += (float)y16[s * OUT_DIM + lane];
    }
    out[n * OUT_DIM + lane] = 0.25f * sum;
}

// ---------------------------------------------------------------------------
extern "C" void kernel_launch(void* const* d_in, const int* in_sizes, int n_in,
                              void* d_out, int out_size, void* d_ws, size_t ws_size,
                              hipStream_t stream)
{
    const float* features = (const float*)d_in[0];
    const int*   src      = (const int*)  d_in[1];
    const int*   dst      = (const int*)  d_in[2];
    const float* proj     = (const float*)d_in[3];

    float* out = (float*)d_out;

    // d_ws layout: y16 (6.4 MB) | cnt (200 KB) | eidx (4.8 MB)  = 11.4 MB
    _Float16*       y16  = (_Float16*)d_ws;
    int*            cnt  = (int*)((char*)d_ws + (size_t)N_NODES * OUT_DIM * 2);
    unsigned short* eidx = (unsigned short*)((char*)cnt + (size_t)N_NODES * 4);

    hipMemsetAsync(cnt, 0, (size_t)N_NODES * 4, stream);

    const int histBlocks = (N_EDGES + 255) / 256;        // 1563
    hist_scatter<<<histBlocks, 256, 0, stream>>>(src, dst, cnt, eidx);

    const int nodeBlocks = (N_NODES + 127) / 128;        // 391
    node_proj_mfma<<<nodeBlocks, 256, 0, stream>>>(features, proj, y16);

    const int pullBlocks = (N_NODES + 3) / 4;            // 12500
    pull_kernel<<<pullBlocks, 256, 0, stream>>>(cnt, eidx, y16, out);
}

// Round 4
// 74.062 us; speedup vs baseline: 3.0973x; 1.2787x over previous
//
#include <hip/hip_runtime.h>

#define IN_DIM   16
#define OUT_DIM  64
#define N_NODES  50000
#define N_EDGES  400000
#define SCALE    0.1f
#define SQRT2C   1.41421356237309515f   // sqrt(2*c), c = 1.0
#define KPAD     288                    // 9 * 32 (K-steps of mfma 16x16x32)
#define DEG_PAD  48                     // max in-degree slots (Poisson(8): P(>=48) ~ 1e-25)

typedef _Float16 f16x8 __attribute__((ext_vector_type(8)));
typedef float    f32x4 __attribute__((ext_vector_type(4)));

// ---------------------------------------------------------------------------
// Kernel P: reorder + fp16-convert proj once into B16[col][KPAD] (36 KB).
// K-permutation: t in [0,256): quad (i=t>>4, j=t&15) -> orig row 17+t
//                t == 256   : const -> orig row 0
//                t in (256,273): linear -> orig row t-256 ; [273,288): pad
// Fragment for (col, k-chunk) is then 16 contiguous bytes at col*576 + 2k.
// ---------------------------------------------------------------------------
__global__ __launch_bounds__(320) void prep_proj(
    const float* __restrict__ proj, _Float16* __restrict__ B16)
{
    const int t   = threadIdx.x;
    const int col = blockIdx.x;
    if (t >= KPAD) return;
    float pv;
    if      (t < 256)  pv = proj[(17 + t) * OUT_DIM + col];
    else if (t == 256) pv = proj[0 * OUT_DIM + col];
    else if (t < 273)  pv = proj[(t - 256) * OUT_DIM + col];
    else               pv = 0.0f;
    B16[col * KPAD + t] = (_Float16)pv;
}

// ---------------------------------------------------------------------------
// Kernel A: y16 = fp16( poly2(features) @ proj ) via fp16 MFMA.
// No LDS, no barriers: B fragments are loaded straight from L2-resident B16.
// Block = 256 thr = 4 waves; wave = 32 nodes (2 m-tiles); block = 128 nodes.
// ---------------------------------------------------------------------------
__global__ __launch_bounds__(256) void node_proj_mfma(
    const float* __restrict__ features, const _Float16* __restrict__ B16,
    _Float16* __restrict__ y16)
{
    const int tid  = threadIdx.x;
    const int wave = tid >> 6;
    const int lane = tid & 63;
    const int kg   = lane >> 4;          // k-group 0..3
    const int bcol = lane & 15;

    const int m0 = blockIdx.x * 128 + wave * 32;   // first node of m-tile 0

    float z0[IN_DIM], z1[IN_DIM];
    {
        int n0 = m0 + (lane & 15);        if (n0 >= N_NODES) n0 = N_NODES - 1;
        int n1 = m0 + 16 + (lane & 15);   if (n1 >= N_NODES) n1 = N_NODES - 1;
        const float4* f0 = (const float4*)(features + n0 * IN_DIM);
        const float4* f1 = (const float4*)(features + n1 * IN_DIM);
        #pragma unroll
        for (int q = 0; q < 4; ++q) {
            float4 v0 = f0[q], v1 = f1[q];
            z0[q*4+0] = SCALE * v0.x; z0[q*4+1] = SCALE * v0.y;
            z0[q*4+2] = SCALE * v0.z; z0[q*4+3] = SCALE * v0.w;
            z1[q*4+0] = SCALE * v1.x; z1[q*4+1] = SCALE * v1.y;
            z1[q*4+2] = SCALE * v1.z; z1[q*4+3] = SCALE * v1.w;
        }
    }

    f32x4 acc0[4] = {};
    f32x4 acc1[4] = {};

    #pragma unroll
    for (int kk = 0; kk < 9; ++kk) {
        // ---- A fragments in registers: a[j] = h[node][kk*32 + kg*8 + j]
        f16x8 a0, a1;
        if (kk < 8) {
            const int zi_idx = kk * 2 + (kg >> 1);
            const int jb     = (kg & 1) * 8;
            const float zi0 = z0[zi_idx], zi1 = z1[zi_idx];
            #pragma unroll
            for (int j = 0; j < 8; ++j) {
                a0[j] = (_Float16)(zi0 * z0[jb + j]);
                a1[j] = (_Float16)(zi1 * z1[jb + j]);
            }
        } else {
            if (kg == 0) {
                a0[0] = (_Float16)1.0f; a1[0] = (_Float16)1.0f;
                #pragma unroll
                for (int j = 1; j < 8; ++j) {
                    a0[j] = (_Float16)(SQRT2C * z0[j - 1]);
                    a1[j] = (_Float16)(SQRT2C * z1[j - 1]);
                }
            } else if (kg == 1) {
                #pragma unroll
                for (int j = 0; j < 8; ++j) {
                    a0[j] = (_Float16)(SQRT2C * z0[7 + j]);
                    a1[j] = (_Float16)(SQRT2C * z1[7 + j]);
                }
            } else if (kg == 2) {
                a0[0] = (_Float16)(SQRT2C * z0[15]);
                a1[0] = (_Float16)(SQRT2C * z1[15]);
                #pragma unroll
                for (int j = 1; j < 8; ++j) { a0[j] = (_Float16)0.0f; a1[j] = (_Float16)0.0f; }
            } else {
                #pragma unroll
                for (int j = 0; j < 8; ++j) { a0[j] = (_Float16)0.0f; a1[j] = (_Float16)0.0f; }
            }
        }

        // ---- B fragments straight from global (L2 broadcast), one per N-tile
        #pragma unroll
        for (int nt = 0; nt < 4; ++nt) {
            const f16x8 b = *(const f16x8*)&B16[(nt * 16 + bcol) * KPAD + kk * 32 + kg * 8];
            acc0[nt] = __builtin_amdgcn_mfma_f32_16x16x32_f16(a0, b, acc0[nt], 0, 0, 0);
            acc1[nt] = __builtin_amdgcn_mfma_f32_16x16x32_f16(a1, b, acc1[nt], 0, 0, 0);
        }
    }

    // ---- epilogue: C/D layout row = kg*4 + r (node), col = nt*16 + bcol
    #pragma unroll
    for (int nt = 0; nt < 4; ++nt) {
        #pragma unroll
        for (int r = 0; r < 4; ++r) {
            const int c  = nt * 16 + bcol;
            const int nA = m0 + kg * 4 + r;
            const int nB = m0 + 16 + kg * 4 + r;
            if (nA < N_NODES) y16[nA * OUT_DIM + c] = (_Float16)acc0[nt][r];
            if (nB < N_NODES) y16[nB * OUT_DIM + c] = (_Float16)acc1[nt][r];
        }
    }
}

// ---------------------------------------------------------------------------
// Kernel B1: histogram + scatter src into padded per-dst slots (u16 ids).
// ---------------------------------------------------------------------------
__global__ __launch_bounds__(256) void hist_scatter(
    const int* __restrict__ src, const int* __restrict__ dst,
    int* __restrict__ cnt, unsigned short* __restrict__ eidx)
{
    const int e = blockIdx.x * 256 + threadIdx.x;
    if (e >= N_EDGES) return;
    const int d = dst[e];
    const int p = atomicAdd(&cnt[d], 1);
    if (p < DEG_PAD) eidx[d * DEG_PAD + p] = (unsigned short)src[e];
}

// ---------------------------------------------------------------------------
// Kernel B2: pull-aggregate. One wave per node; lanes = 64 output columns.
// out[n] = 0.25 * ( y[n] + sum_{e: dst=n} y[src_e] )
// ---------------------------------------------------------------------------
__global__ __launch_bounds__(256) void pull_kernel(
    const int* __restrict__ cnt, const unsigned short* __restrict__ eidx,
    const _Float16* __restrict__ y16, float* __restrict__ out)
{
    const int wave = threadIdx.x >> 6;
    const int lane = threadIdx.x & 63;
    const int n    = blockIdx.x * 4 + wave;
    if (n >= N_NODES) return;

    int deg = cnt[n];
    if (deg > DEG_PAD) deg = DEG_PAD;

    int myIdx = 0;
    if (lane < DEG_PAD) myIdx = eidx[n * DEG_PAD + lane];

    float sum = (float)y16[n * OUT_DIM + lane];   // residual term

    int k = 0;
    for (; k + 1 < deg; k += 2) {                 // 2-wide for MLP
        const int s0 = __shfl(myIdx, k, 64);
        const int s1 = __shfl(myIdx, k + 1, 64);
        const float va = (float)y16[s0 * OUT_DIM + lane];
        const float vb = (float)y16[s1 * OUT_DIM + lane];
        sum += va + vb;
    }
    if (k < deg) {
        const int s = __shfl(myIdx, k, 64);
        sum += (float)y16[s * OUT_DIM + lane];
    }
    out[n * OUT_DIM + lane] = 0.25f * sum;
}

// ---------------------------------------------------------------------------
extern "C" void kernel_launch(void* const* d_in, const int* in_sizes, int n_in,
                              void* d_out, int out_size, void* d_ws, size_t ws_size,
                              hipStream_t stream)
{
    const float* features = (const float*)d_in[0];
    const int*   src      = (const int*)  d_in[1];
    const int*   dst      = (const int*)  d_in[2];
    const float* proj     = (const float*)d_in[3];

    float* out = (float*)d_out;

    // d_ws layout: y16 (6.4 MB) | cnt (200 KB) | eidx (4.8 MB) | B16 (36 KB)
    _Float16*       y16  = (_Float16*)d_ws;
    int*            cnt  = (int*)((char*)d_ws + (size_t)N_NODES * OUT_DIM * 2);
    unsigned short* eidx = (unsigned short*)((char*)cnt + (size_t)N_NODES * 4);
    _Float16*       B16  = (_Float16*)((char*)eidx + (size_t)N_NODES * DEG_PAD * 2);

    hipMemsetAsync(cnt, 0, (size_t)N_NODES * 4, stream);

    prep_proj<<<OUT_DIM, 320, 0, stream>>>(proj, B16);

    const int histBlocks = (N_EDGES + 255) / 256;        // 1563
    hist_scatter<<<histBlocks, 256, 0, stream>>>(src, dst, cnt, eidx);

    const int nodeBlocks = (N_NODES + 127) / 128;        // 391
    node_proj_mfma<<<nodeBlocks, 256, 0, stream>>>(features, B16, y16);

    const int pullBlocks = (N_NODES + 3) / 4;            // 12500
    pull_kernel<<<pullBlocks, 256, 0, stream>>>(cnt, eidx, y16, out);
}

// Round 5
// 73.576 us; speedup vs baseline: 3.1177x; 1.0066x over previous
//
#include <hip/hip_runtime.h>

#define IN_DIM   16
#define OUT_DIM  64
#define N_NODES  50000
#define N_EDGES  400000
#define SCALE    0.1f
#define SQRT2C   1.41421356237309515f   // sqrt(2*c), c = 1.0
#define KPAD     288                    // 9 * 32 (K-steps of mfma 16x16x32)
#define DEG_PAD  48                     // max in-degree slots (Poisson(8): P(>=48) ~ 1e-25)

typedef _Float16 f16x8 __attribute__((ext_vector_type(8)));
typedef float    f32x4 __attribute__((ext_vector_type(4)));

// ---------------------------------------------------------------------------
// Kernel Z: zero the per-dst counters. (hipMemsetAsync's fillBufferAligned
// used a tiny grid: 43 us for 200 KB. This does it in ~2 us.)
// ---------------------------------------------------------------------------
__global__ __launch_bounds__(256) void zero_cnt(int* __restrict__ cnt)
{
    const int i = blockIdx.x * 256 + threadIdx.x;
    if (i < N_NODES) cnt[i] = 0;
}

// ---------------------------------------------------------------------------
// Kernel P: reorder + fp16-convert proj once into B16[col][KPAD] (36 KB).
// K-permutation: t in [0,256): quad (i=t>>4, j=t&15) -> orig row 17+t
//                t == 256   : const -> orig row 0
//                t in (256,273): linear -> orig row t-256 ; [273,288): pad
// Fragment for (col, k-chunk) is then 16 contiguous bytes at col*576 + 2k.
// ---------------------------------------------------------------------------
__global__ __launch_bounds__(320) void prep_proj(
    const float* __restrict__ proj, _Float16* __restrict__ B16)
{
    const int t   = threadIdx.x;
    const int col = blockIdx.x;
    if (t >= KPAD) return;
    float pv;
    if      (t < 256)  pv = proj[(17 + t) * OUT_DIM + col];
    else if (t == 256) pv = proj[0 * OUT_DIM + col];
    else if (t < 273)  pv = proj[(t - 256) * OUT_DIM + col];
    else               pv = 0.0f;
    B16[col * KPAD + t] = (_Float16)pv;
}

// ---------------------------------------------------------------------------
// Kernel A: y16 = fp16( poly2(features) @ proj ) via fp16 MFMA.
// No LDS, no barriers: B fragments are loaded straight from L2-resident B16.
// Block = 256 thr = 4 waves; wave = 32 nodes (2 m-tiles); block = 128 nodes.
// ---------------------------------------------------------------------------
__global__ __launch_bounds__(256) void node_proj_mfma(
    const float* __restrict__ features, const _Float16* __restrict__ B16,
    _Float16* __restrict__ y16)
{
    const int tid  = threadIdx.x;
    const int wave = tid >> 6;
    const int lane = tid & 63;
    const int kg   = lane >> 4;          // k-group 0..3
    const int bcol = lane & 15;

    const int m0 = blockIdx.x * 128 + wave * 32;   // first node of m-tile 0

    float z0[IN_DIM], z1[IN_DIM];
    {
        int n0 = m0 + (lane & 15);        if (n0 >= N_NODES) n0 = N_NODES - 1;
        int n1 = m0 + 16 + (lane & 15);   if (n1 >= N_NODES) n1 = N_NODES - 1;
        const float4* f0 = (const float4*)(features + n0 * IN_DIM);
        const float4* f1 = (const float4*)(features + n1 * IN_DIM);
        #pragma unroll
        for (int q = 0; q < 4; ++q) {
            float4 v0 = f0[q], v1 = f1[q];
            z0[q*4+0] = SCALE * v0.x; z0[q*4+1] = SCALE * v0.y;
            z0[q*4+2] = SCALE * v0.z; z0[q*4+3] = SCALE * v0.w;
            z1[q*4+0] = SCALE * v1.x; z1[q*4+1] = SCALE * v1.y;
            z1[q*4+2] = SCALE * v1.z; z1[q*4+3] = SCALE * v1.w;
        }
    }

    f32x4 acc0[4] = {};
    f32x4 acc1[4] = {};

    #pragma unroll
    for (int kk = 0; kk < 9; ++kk) {
        // ---- A fragments in registers: a[j] = h[node][kk*32 + kg*8 + j]
        f16x8 a0, a1;
        if (kk < 8) {
            const int zi_idx = kk * 2 + (kg >> 1);
            const int jb     = (kg & 1) * 8;
            const float zi0 = z0[zi_idx], zi1 = z1[zi_idx];
            #pragma unroll
            for (int j = 0; j < 8; ++j) {
                a0[j] = (_Float16)(zi0 * z0[jb + j]);
                a1[j] = (_Float16)(zi1 * z1[jb + j]);
            }
        } else {
            if (kg == 0) {
                a0[0] = (_Float16)1.0f; a1[0] = (_Float16)1.0f;
                #pragma unroll
                for (int j = 1; j < 8; ++j) {
                    a0[j] = (_Float16)(SQRT2C * z0[j - 1]);
                    a1[j] = (_Float16)(SQRT2C * z1[j - 1]);
                }
            } else if (kg == 1) {
                #pragma unroll
                for (int j = 0; j < 8; ++j) {
                    a0[j] = (_Float16)(SQRT2C * z0[7 + j]);
                    a1[j] = (_Float16)(SQRT2C * z1[7 + j]);
                }
            } else if (kg == 2) {
                a0[0] = (_Float16)(SQRT2C * z0[15]);
                a1[0] = (_Float16)(SQRT2C * z1[15]);
                #pragma unroll
                for (int j = 1; j < 8; ++j) { a0[j] = (_Float16)0.0f; a1[j] = (_Float16)0.0f; }
            } else {
                #pragma unroll
                for (int j = 0; j < 8; ++j) { a0[j] = (_Float16)0.0f; a1[j] = (_Float16)0.0f; }
            }
        }

        // ---- B fragments straight from global (L2 broadcast), one per N-tile
        #pragma unroll
        for (int nt = 0; nt < 4; ++nt) {
            const f16x8 b = *(const f16x8*)&B16[(nt * 16 + bcol) * KPAD + kk * 32 + kg * 8];
            acc0[nt] = __builtin_amdgcn_mfma_f32_16x16x32_f16(a0, b, acc0[nt], 0, 0, 0);
            acc1[nt] = __builtin_amdgcn_mfma_f32_16x16x32_f16(a1, b, acc1[nt], 0, 0, 0);
        }
    }

    // ---- epilogue: C/D layout row = kg*4 + r (node), col = nt*16 + bcol
    #pragma unroll
    for (int nt = 0; nt < 4; ++nt) {
        #pragma unroll
        for (int r = 0; r < 4; ++r) {
            const int c  = nt * 16 + bcol;
            const int nA = m0 + kg * 4 + r;
            const int nB = m0 + 16 + kg * 4 + r;
            if (nA < N_NODES) y16[nA * OUT_DIM + c] = (_Float16)acc0[nt][r];
            if (nB < N_NODES) y16[nB * OUT_DIM + c] = (_Float16)acc1[nt][r];
        }
    }
}

// ---------------------------------------------------------------------------
// Kernel B1: histogram + scatter src into padded per-dst slots (u16 ids).
// ---------------------------------------------------------------------------
__global__ __launch_bounds__(256) void hist_scatter(
    const int* __restrict__ src, const int* __restrict__ dst,
    int* __restrict__ cnt, unsigned short* __restrict__ eidx)
{
    const int e = blockIdx.x * 256 + threadIdx.x;
    if (e >= N_EDGES) return;
    const int d = dst[e];
    const int p = atomicAdd(&cnt[d], 1);
    if (p < DEG_PAD) eidx[d * DEG_PAD + p] = (unsigned short)src[e];
}

// ---------------------------------------------------------------------------
// Kernel B2: pull-aggregate. One wave per node; lanes = 64 output columns.
// out[n] = 0.25 * ( y[n] + sum_{e: dst=n} y[src_e] )
// ---------------------------------------------------------------------------
__global__ __launch_bounds__(256) void pull_kernel(
    const int* __restrict__ cnt, const unsigned short* __restrict__ eidx,
    const _Float16* __restrict__ y16, float* __restrict__ out)
{
    const int wave = threadIdx.x >> 6;
    const int lane = threadIdx.x & 63;
    const int n    = blockIdx.x * 4 + wave;
    if (n >= N_NODES) return;

    int deg = cnt[n];
    if (deg > DEG_PAD) deg = DEG_PAD;

    int myIdx = 0;
    if (lane < DEG_PAD) myIdx = eidx[n * DEG_PAD + lane];

    float sum = (float)y16[n * OUT_DIM + lane];   // residual term

    int k = 0;
    for (; k + 1 < deg; k += 2) {                 // 2-wide for MLP
        const int s0 = __shfl(myIdx, k, 64);
        const int s1 = __shfl(myIdx, k + 1, 64);
        const float va = (float)y16[s0 * OUT_DIM + lane];
        const float vb = (float)y16[s1 * OUT_DIM + lane];
        sum += va + vb;
    }
    if (k < deg) {
        const int s = __shfl(myIdx, k, 64);
        sum += (float)y16[s * OUT_DIM + lane];
    }
    out[n * OUT_DIM + lane] = 0.25f * sum;
}

// ---------------------------------------------------------------------------
extern "C" void kernel_launch(void* const* d_in, const int* in_sizes, int n_in,
                              void* d_out, int out_size, void* d_ws, size_t ws_size,
                              hipStream_t stream)
{
    const float* features = (const float*)d_in[0];
    const int*   src      = (const int*)  d_in[1];
    const int*   dst      = (const int*)  d_in[2];
    const float* proj     = (const float*)d_in[3];

    float* out = (float*)d_out;

    // d_ws layout: y16 (6.4 MB) | cnt (200 KB) | eidx (4.8 MB) | B16 (36 KB)
    _Float16*       y16  = (_Float16*)d_ws;
    int*            cnt  = (int*)((char*)d_ws + (size_t)N_NODES * OUT_DIM * 2);
    unsigned short* eidx = (unsigned short*)((char*)cnt + (size_t)N_NODES * 4);
    _Float16*       B16  = (_Float16*)((char*)eidx + (size_t)N_NODES * DEG_PAD * 2);

    const int zeroBlocks = (N_NODES + 255) / 256;        // 196
    zero_cnt<<<zeroBlocks, 256, 0, stream>>>(cnt);

    prep_proj<<<OUT_DIM, 320, 0, stream>>>(proj, B16);

    const int histBlocks = (N_EDGES + 255) / 256;        // 1563
    hist_scatter<<<histBlocks, 256, 0, stream>>>(src, dst, cnt, eidx);

    const int nodeBlocks = (N_NODES + 127) / 128;        // 391
    node_proj_mfma<<<nodeBlocks, 256, 0, stream>>>(features, B16, y16);

    const int pullBlocks = (N_NODES + 3) / 4;            // 12500
    pull_kernel<<<pullBlocks, 256, 0, stream>>>(cnt, eidx, y16, out);
}

// Round 6
// 60.965 us; speedup vs baseline: 3.7626x; 1.2069x over previous
//
#include <hip/hip_runtime.h>

#define IN_DIM   16
#define OUT_DIM  64
#define N_NODES  50000
#define N_EDGES  400000
#define SCALE    0.1f
#define SQRT2C   1.41421356237309515f   // sqrt(2*c), c = 1.0
#define KPAD     288                    // 9 * 32 (K-steps of mfma 16x16x32)
#define DEG_PAD  48                     // max in-degree slots (validated: absmax passed)

#define NODE_BLOCKS 391                 // ceil(50000/128)
#define HIST_BLOCKS 1563                // ceil(400000/256)

typedef _Float16 f16x8 __attribute__((ext_vector_type(8)));
typedef _Float16 f16x4 __attribute__((ext_vector_type(4)));
typedef float    f32x4 __attribute__((ext_vector_type(4)));

// ---------------------------------------------------------------------------
// K1: zero per-dst counters + reorder/convert proj into B16[col][KPAD] fp16.
// K-permutation: t in [0,256): quad (i=t>>4,j=t&15) -> row 17+t ; t==256: row 0
//                t in (256,273): row t-256 ; [273,288): zero pad.
// ---------------------------------------------------------------------------
__global__ __launch_bounds__(256) void setup_kernel(
    const float* __restrict__ proj, int* __restrict__ cnt,
    _Float16* __restrict__ B16)
{
    const int t = blockIdx.x * 256 + threadIdx.x;
    if (t < N_NODES) cnt[t] = 0;
    if (t < OUT_DIM * 512) {            // 64 cols x 512 (pad of 288)
        const int col = t >> 9;
        const int k   = t & 511;
        if (k < KPAD) {
            float pv;
            if      (k < 256)  pv = proj[(17 + k) * OUT_DIM + col];
            else if (k == 256) pv = proj[0 * OUT_DIM + col];
            else if (k < 273)  pv = proj[(k - 256) * OUT_DIM + col];
            else               pv = 0.0f;
            B16[col * KPAD + k] = (_Float16)pv;
        }
    }
}

// ---------------------------------------------------------------------------
// K2: fused  [blocks 0..390]   node: y16 = fp16(poly2(features) @ proj), MFMA
//            [blocks 391..1953] hist: cnt/eidx inverse-adjacency build
// Independent work co-resident on the CUs: MFMA pipe + memory/atomic pipe.
// ---------------------------------------------------------------------------
__device__ __forceinline__ void node_path(
    int blk, const float* __restrict__ features,
    const _Float16* __restrict__ B16, _Float16* __restrict__ y16)
{
    const int tid  = threadIdx.x;
    const int wave = tid >> 6;
    const int lane = tid & 63;
    const int kg   = lane >> 4;
    const int bcol = lane & 15;

    const int m0 = blk * 128 + wave * 32;

    float z0[IN_DIM], z1[IN_DIM];
    {
        int n0 = m0 + (lane & 15);        if (n0 >= N_NODES) n0 = N_NODES - 1;
        int n1 = m0 + 16 + (lane & 15);   if (n1 >= N_NODES) n1 = N_NODES - 1;
        const float4* f0 = (const float4*)(features + n0 * IN_DIM);
        const float4* f1 = (const float4*)(features + n1 * IN_DIM);
        #pragma unroll
        for (int q = 0; q < 4; ++q) {
            float4 v0 = f0[q], v1 = f1[q];
            z0[q*4+0] = SCALE * v0.x; z0[q*4+1] = SCALE * v0.y;
            z0[q*4+2] = SCALE * v0.z; z0[q*4+3] = SCALE * v0.w;
            z1[q*4+0] = SCALE * v1.x; z1[q*4+1] = SCALE * v1.y;
            z1[q*4+2] = SCALE * v1.z; z1[q*4+3] = SCALE * v1.w;
        }
    }

    f32x4 acc0[4] = {};
    f32x4 acc1[4] = {};

    #pragma unroll
    for (int kk = 0; kk < 9; ++kk) {
        f16x8 a0, a1;
        if (kk < 8) {
            const int zi_idx = kk * 2 + (kg >> 1);
            const int jb     = (kg & 1) * 8;
            const float zi0 = z0[zi_idx], zi1 = z1[zi_idx];
            #pragma unroll
            for (int j = 0; j < 8; ++j) {
                a0[j] = (_Float16)(zi0 * z0[jb + j]);
                a1[j] = (_Float16)(zi1 * z1[jb + j]);
            }
        } else {
            if (kg == 0) {
                a0[0] = (_Float16)1.0f; a1[0] = (_Float16)1.0f;
                #pragma unroll
                for (int j = 1; j < 8; ++j) {
                    a0[j] = (_Float16)(SQRT2C * z0[j - 1]);
                    a1[j] = (_Float16)(SQRT2C * z1[j - 1]);
                }
            } else if (kg == 1) {
                #pragma unroll
                for (int j = 0; j < 8; ++j) {
                    a0[j] = (_Float16)(SQRT2C * z0[7 + j]);
                    a1[j] = (_Float16)(SQRT2C * z1[7 + j]);
                }
            } else if (kg == 2) {
                a0[0] = (_Float16)(SQRT2C * z0[15]);
                a1[0] = (_Float16)(SQRT2C * z1[15]);
                #pragma unroll
                for (int j = 1; j < 8; ++j) { a0[j] = (_Float16)0.0f; a1[j] = (_Float16)0.0f; }
            } else {
                #pragma unroll
                for (int j = 0; j < 8; ++j) { a0[j] = (_Float16)0.0f; a1[j] = (_Float16)0.0f; }
            }
        }

        #pragma unroll
        for (int nt = 0; nt < 4; ++nt) {
            const f16x8 b = *(const f16x8*)&B16[(nt * 16 + bcol) * KPAD + kk * 32 + kg * 8];
            acc0[nt] = __builtin_amdgcn_mfma_f32_16x16x32_f16(a0, b, acc0[nt], 0, 0, 0);
            acc1[nt] = __builtin_amdgcn_mfma_f32_16x16x32_f16(a1, b, acc1[nt], 0, 0, 0);
        }
    }

    #pragma unroll
    for (int nt = 0; nt < 4; ++nt) {
        #pragma unroll
        for (int r = 0; r < 4; ++r) {
            const int c  = nt * 16 + bcol;
            const int nA = m0 + kg * 4 + r;
            const int nB = m0 + 16 + kg * 4 + r;
            if (nA < N_NODES) y16[nA * OUT_DIM + c] = (_Float16)acc0[nt][r];
            if (nB < N_NODES) y16[nB * OUT_DIM + c] = (_Float16)acc1[nt][r];
        }
    }
}

__device__ __forceinline__ void hist_path(
    int blk, const int* __restrict__ src, const int* __restrict__ dst,
    int* __restrict__ cnt, unsigned short* __restrict__ eidx)
{
    const int e = blk * 256 + threadIdx.x;
    if (e >= N_EDGES) return;
    const int d = dst[e];
    const int p = atomicAdd(&cnt[d], 1);
    if (p < DEG_PAD) eidx[d * DEG_PAD + p] = (unsigned short)src[e];
}

__global__ __launch_bounds__(256) void fused_node_hist(
    const float* __restrict__ features, const _Float16* __restrict__ B16,
    _Float16* __restrict__ y16,
    const int* __restrict__ src, const int* __restrict__ dst,
    int* __restrict__ cnt, unsigned short* __restrict__ eidx)
{
    if (blockIdx.x < NODE_BLOCKS)
        node_path(blockIdx.x, features, B16, y16);
    else
        hist_path(blockIdx.x - NODE_BLOCKS, src, dst, cnt, eidx);
}

// ---------------------------------------------------------------------------
// K3: pull-aggregate, 4 edges per gather instruction.
// Wave = 1 node. lane = (g = lane>>4 edge sub-slot, q = lane&15 col-quad).
// Group g accumulates edges k+g; each lane loads f16x4 (8 B) of 4 columns.
// Cross-group reduce: shfl_xor 16, 32. g==0 lanes hold residual + write f32x4.
// ---------------------------------------------------------------------------
__global__ __launch_bounds__(256) void pull_kernel(
    const int* __restrict__ cnt, const unsigned short* __restrict__ eidx,
    const _Float16* __restrict__ y16, float* __restrict__ out)
{
    const int wave = threadIdx.x >> 6;
    const int lane = threadIdx.x & 63;
    const int n    = blockIdx.x * 4 + wave;
    if (n >= N_NODES) return;

    const int g = lane >> 4;
    const int q = lane & 15;

    int deg = cnt[n];
    if (deg > DEG_PAD) deg = DEG_PAD;

    int myIdx = 0;
    if (lane < DEG_PAD) myIdx = eidx[n * DEG_PAD + lane];

    float ax = 0.f, ay = 0.f, az = 0.f, aw = 0.f;
    if (g == 0) {   // residual term, counted once
        const f16x4 r = *(const f16x4*)(y16 + (size_t)n * OUT_DIM + q * 4);
        ax = (float)r[0]; ay = (float)r[1]; az = (float)r[2]; aw = (float)r[3];
    }

    for (int k = 0; k < deg; k += 4) {
        const int e = k + g;                       // e <= 47 always (deg<=48)
        const int s = __shfl(myIdx, e, 64);        // per-lane src lane: bpermute
        const f16x4 v = *(const f16x4*)(y16 + (size_t)s * OUT_DIM + q * 4);
        if (e < deg) {                             // mask AFTER load, before any math
            ax += (float)v[0]; ay += (float)v[1];
            az += (float)v[2]; aw += (float)v[3];
        }
    }

    // reduce partial sums across the 4 edge groups (lanes q, q+16, q+32, q+48)
    ax += __shfl_xor(ax, 16, 64); ay += __shfl_xor(ay, 16, 64);
    az += __shfl_xor(az, 16, 64); aw += __shfl_xor(aw, 16, 64);
    ax += __shfl_xor(ax, 32, 64); ay += __shfl_xor(ay, 32, 64);
    az += __shfl_xor(az, 32, 64); aw += __shfl_xor(aw, 32, 64);

    if (g == 0) {
        float4 o; o.x = 0.25f * ax; o.y = 0.25f * ay; o.z = 0.25f * az; o.w = 0.25f * aw;
        *(float4*)(out + (size_t)n * OUT_DIM + q * 4) = o;
    }
}

// ---------------------------------------------------------------------------
extern "C" void kernel_launch(void* const* d_in, const int* in_sizes, int n_in,
                              void* d_out, int out_size, void* d_ws, size_t ws_size,
                              hipStream_t stream)
{
    const float* features = (const float*)d_in[0];
    const int*   src      = (const int*)  d_in[1];
    const int*   dst      = (const int*)  d_in[2];
    const float* proj     = (const float*)d_in[3];

    float* out = (float*)d_out;

    // d_ws layout: y16 (6.4 MB) | cnt (200 KB) | eidx (4.8 MB) | B16 (36 KB)
    _Float16*       y16  = (_Float16*)d_ws;
    int*            cnt  = (int*)((char*)d_ws + (size_t)N_NODES * OUT_DIM * 2);
    unsigned short* eidx = (unsigned short*)((char*)cnt + (size_t)N_NODES * 4);
    _Float16*       B16  = (_Float16*)((char*)eidx + (size_t)N_NODES * DEG_PAD * 2);

    const int setupBlocks = (N_NODES + 255) / 256;       // 196 (covers 64*512 too)
    setup_kernel<<<setupBlocks, 256, 0, stream>>>(proj, cnt, B16);

    fused_node_hist<<<NODE_BLOCKS + HIST_BLOCKS, 256, 0, stream>>>(
        features, B16, y16, src, dst, cnt, eidx);

    const int pullBlocks = (N_NODES + 3) / 4;            // 12500
    pull_kernel<<<pullBlocks, 256, 0, stream>>>(cnt, eidx, y16, out);
}

// Round 7
// 54.838 us; speedup vs baseline: 4.1830x; 1.1117x over previous
//
#include <hip/hip_runtime.h>

#define IN_DIM   16
#define OUT_DIM  64
#define N_NODES  50000
#define N_EDGES  400000
#define SCALE    0.1f
#define SQRT2C   1.41421356237309515f   // sqrt(2*c), c = 1.0
#define KPAD     288                    // 9 * 32 (K-steps of mfma 16x16x32)
#define DEG_PAD  48                     // max in-degree slots (validated: absmax passed)

#define NODE_BLOCKS 782                 // ceil(50000/64), 16 nodes per wave
#define HIST_BLOCKS 1563                // ceil(400000/256)

typedef _Float16 f16x8 __attribute__((ext_vector_type(8)));
typedef float    f32x4 __attribute__((ext_vector_type(4)));

// ---------------------------------------------------------------------------
// K1: zero per-dst counters + reorder/convert proj into B16[col][KPAD] fp16.
// K-permutation: t in [0,256): quad (i=t>>4,j=t&15) -> row 17+t ; t==256: row 0
//                t in (256,273): row t-256 ; [273,288): zero pad.
// ---------------------------------------------------------------------------
__global__ __launch_bounds__(256) void setup_kernel(
    const float* __restrict__ proj, int* __restrict__ cnt,
    _Float16* __restrict__ B16)
{
    const int t = blockIdx.x * 256 + threadIdx.x;
    if (t < N_NODES) cnt[t] = 0;
    if (t < OUT_DIM * 512) {            // 64 cols x 512 (pad of 288)
        const int col = t >> 9;
        const int k   = t & 511;
        if (k < KPAD) {
            float pv;
            if      (k < 256)  pv = proj[(17 + k) * OUT_DIM + col];
            else if (k == 256) pv = proj[0 * OUT_DIM + col];
            else if (k < 273)  pv = proj[(k - 256) * OUT_DIM + col];
            else               pv = 0.0f;
            B16[col * KPAD + k] = (_Float16)pv;
        }
    }
}

// ---------------------------------------------------------------------------
// K2: fused  [blocks 0..781]    node: y16 = fp16(poly2(features) @ proj), MFMA
//            [blocks 782..2344] hist: cnt/eidx inverse-adjacency build
// Node path: 16 nodes per wave (1 m-tile) -> 3128 waves = ~3 waves/SIMD for
// L2-load latency hiding (was 1.5). B fragments read straight from L2 B16.
// ---------------------------------------------------------------------------
__device__ __forceinline__ void node_path(
    int blk, const float* __restrict__ features,
    const _Float16* __restrict__ B16, _Float16* __restrict__ y16)
{
    const int tid  = threadIdx.x;
    const int wave = tid >> 6;
    const int lane = tid & 63;
    const int kg   = lane >> 4;          // k-group 0..3
    const int bcol = lane & 15;

    const int m0 = blk * 64 + wave * 16;   // 16 nodes per wave

    float z[IN_DIM];
    {
        int n = m0 + (lane & 15); if (n >= N_NODES) n = N_NODES - 1;
        const float4* f4 = (const float4*)(features + n * IN_DIM);
        #pragma unroll
        for (int q = 0; q < 4; ++q) {
            float4 v = f4[q];
            z[q*4+0] = SCALE * v.x; z[q*4+1] = SCALE * v.y;
            z[q*4+2] = SCALE * v.z; z[q*4+3] = SCALE * v.w;
        }
    }

    f32x4 acc[4] = {};

    #pragma unroll
    for (int kk = 0; kk < 9; ++kk) {
        // ---- A fragment in registers: a[j] = h[node][kk*32 + kg*8 + j]
        f16x8 a;
        if (kk < 8) {
            const float zi = z[kk * 2 + (kg >> 1)];
            const int jb = (kg & 1) * 8;
            #pragma unroll
            for (int j = 0; j < 8; ++j) a[j] = (_Float16)(zi * z[jb + j]);
        } else {
            if (kg == 0) {
                a[0] = (_Float16)1.0f;
                #pragma unroll
                for (int j = 1; j < 8; ++j) a[j] = (_Float16)(SQRT2C * z[j - 1]);
            } else if (kg == 1) {
                #pragma unroll
                for (int j = 0; j < 8; ++j) a[j] = (_Float16)(SQRT2C * z[7 + j]);
            } else if (kg == 2) {
                a[0] = (_Float16)(SQRT2C * z[15]);
                #pragma unroll
                for (int j = 1; j < 8; ++j) a[j] = (_Float16)0.0f;
            } else {
                #pragma unroll
                for (int j = 0; j < 8; ++j) a[j] = (_Float16)0.0f;
            }
        }

        // ---- B fragments straight from global (L2 broadcast), one per N-tile
        #pragma unroll
        for (int nt = 0; nt < 4; ++nt) {
            const f16x8 b = *(const f16x8*)&B16[(nt * 16 + bcol) * KPAD + kk * 32 + kg * 8];
            acc[nt] = __builtin_amdgcn_mfma_f32_16x16x32_f16(a, b, acc[nt], 0, 0, 0);
        }
    }

    // ---- epilogue: C/D layout row = kg*4 + r (node), col = nt*16 + bcol
    #pragma unroll
    for (int nt = 0; nt < 4; ++nt) {
        #pragma unroll
        for (int r = 0; r < 4; ++r) {
            const int c = nt * 16 + bcol;
            const int n = m0 + kg * 4 + r;
            if (n < N_NODES) y16[n * OUT_DIM + c] = (_Float16)acc[nt][r];
        }
    }
}

__device__ __forceinline__ void hist_path(
    int blk, const int* __restrict__ src, const int* __restrict__ dst,
    int* __restrict__ cnt, unsigned short* __restrict__ eidx)
{
    const int e = blk * 256 + threadIdx.x;
    if (e >= N_EDGES) return;
    const int d = dst[e];
    const int p = atomicAdd(&cnt[d], 1);
    if (p < DEG_PAD) eidx[d * DEG_PAD + p] = (unsigned short)src[e];
}

__global__ __launch_bounds__(256) void fused_node_hist(
    const float* __restrict__ features, const _Float16* __restrict__ B16,
    _Float16* __restrict__ y16,
    const int* __restrict__ src, const int* __restrict__ dst,
    int* __restrict__ cnt, unsigned short* __restrict__ eidx)
{
    if (blockIdx.x < NODE_BLOCKS)
        node_path(blockIdx.x, features, B16, y16);
    else
        hist_path(blockIdx.x - NODE_BLOCKS, src, dst, cnt, eidx);
}

// ---------------------------------------------------------------------------
// K3: pull-aggregate, 8 edge-groups x f16x8 per lane (16 B).
// Wave = 1 node. g = lane>>3 (edge sub-slot), q = lane&7 (col octet).
// Group g accumulates edges k+g (k += 8): avg iterations ~1.3 at deg~8.
// Cross-group reduce: shfl_xor 8,16,32. g==0 lanes add residual + write row.
// ---------------------------------------------------------------------------
__global__ __launch_bounds__(256) void pull_kernel(
    const int* __restrict__ cnt, const unsigned short* __restrict__ eidx,
    const _Float16* __restrict__ y16, float* __restrict__ out)
{
    const int wave = threadIdx.x >> 6;
    const int lane = threadIdx.x & 63;
    const int n    = blockIdx.x * 4 + wave;
    if (n >= N_NODES) return;

    const int g = lane >> 3;
    const int q = lane & 7;

    int deg = cnt[n];
    if (deg > DEG_PAD) deg = DEG_PAD;

    int myIdx = 0;
    if (lane < DEG_PAD) myIdx = eidx[n * DEG_PAD + lane];

    float a0=0.f,a1=0.f,a2=0.f,a3=0.f,a4=0.f,a5=0.f,a6=0.f,a7=0.f;
    if (g == 0) {   // residual term, counted once
        const f16x8 r = *(const f16x8*)(y16 + (size_t)n * OUT_DIM + q * 8);
        a0=(float)r[0]; a1=(float)r[1]; a2=(float)r[2]; a3=(float)r[3];
        a4=(float)r[4]; a5=(float)r[5]; a6=(float)r[6]; a7=(float)r[7];
    }

    for (int k = 0; k < deg; k += 8) {
        const int e = k + g;                       // e <= 47 always
        const int s = __shfl(myIdx, e, 64);        // ds_bpermute
        const f16x8 v = *(const f16x8*)(y16 + (size_t)s * OUT_DIM + q * 8);
        if (e < deg) {                             // mask AFTER load, before math
            a0+=(float)v[0]; a1+=(float)v[1]; a2+=(float)v[2]; a3+=(float)v[3];
            a4+=(float)v[4]; a5+=(float)v[5]; a6+=(float)v[6]; a7+=(float)v[7];
        }
    }

    // reduce across the 8 edge groups (fixed q, xor over g bits)
    #pragma unroll
    for (int off = 8; off <= 32; off <<= 1) {
        a0 += __shfl_xor(a0, off, 64); a1 += __shfl_xor(a1, off, 64);
        a2 += __shfl_xor(a2, off, 64); a3 += __shfl_xor(a3, off, 64);
        a4 += __shfl_xor(a4, off, 64); a5 += __shfl_xor(a5, off, 64);
        a6 += __shfl_xor(a6, off, 64); a7 += __shfl_xor(a7, off, 64);
    }

    if (g == 0) {
        float* o = out + (size_t)n * OUT_DIM + q * 8;
        float4 lo, hi;
        lo.x = 0.25f*a0; lo.y = 0.25f*a1; lo.z = 0.25f*a2; lo.w = 0.25f*a3;
        hi.x = 0.25f*a4; hi.y = 0.25f*a5; hi.z = 0.25f*a6; hi.w = 0.25f*a7;
        *(float4*)o       = lo;
        *(float4*)(o + 4) = hi;
    }
}

// ---------------------------------------------------------------------------
extern "C" void kernel_launch(void* const* d_in, const int* in_sizes, int n_in,
                              void* d_out, int out_size, void* d_ws, size_t ws_size,
                              hipStream_t stream)
{
    const float* features = (const float*)d_in[0];
    const int*   src      = (const int*)  d_in[1];
    const int*   dst      = (const int*)  d_in[2];
    const float* proj     = (const float*)d_in[3];

    float* out = (float*)d_out;

    // d_ws layout: y16 (6.4 MB) | cnt (200 KB) | eidx (4.8 MB) | B16 (36 KB)
    _Float16*       y16  = (_Float16*)d_ws;
    int*            cnt  = (int*)((char*)d_ws + (size_t)N_NODES * OUT_DIM * 2);
    unsigned short* eidx = (unsigned short*)((char*)cnt + (size_t)N_NODES * 4);
    _Float16*       B16  = (_Float16*)((char*)eidx + (size_t)N_NODES * DEG_PAD * 2);

    const int setupBlocks = (N_NODES + 255) / 256;       // 196
    setup_kernel<<<setupBlocks, 256, 0, stream>>>(proj, cnt, B16);

    fused_node_hist<<<NODE_BLOCKS + HIST_BLOCKS, 256, 0, stream>>>(
        features, B16, y16, src, dst, cnt, eidx);

    const int pullBlocks = (N_NODES + 3) / 4;            // 12500
    pull_kernel<<<pullBlocks, 256, 0, stream>>>(cnt, eidx, y16, out);
}